// Round 6
// baseline (187.175 us; speedup 1.0000x reference)
//
#include <hip/hip_runtime.h>
#include <hip/hip_fp16.h>

#define NN 50000
#define NE 800000
#define IN_DIM 128
#define OUT_DIM 64
#define NEG 0.2f
#define CAP 64                  // per-node edge slots (Poisson(16): P(deg>63) ~ 1e-15)

#define BSHIFT 11
#define BNODES 2048             // nodes per coarse bucket
#define NBUCK 25                // ceil(50000 / 2048)
#define BUCKCAP 36864           // mean 32768, +22 sigma headroom
#define CHUNK 4096              // edges per phase-1 block
#define BIN_BLOCKS 196          // ceil(NE / CHUNK)
#define GEMM_BLOCKS 782         // ceil(NN / 64)
#define P2_SPLIT 48             // blocks per bucket in phase 2

// ---- Kernel A: fused [h2 = fp16(x@W) + a_src/a_dst] and [edge bin-sort] ----
__global__ __launch_bounds__(256) void gat_gemm_bin(
    const float* __restrict__ x, const float* __restrict__ W,
    const float* __restrict__ att_src, const float* __restrict__ att_dst,
    const int* __restrict__ src, const int* __restrict__ dst,
    __half* __restrict__ h2, float* __restrict__ a_src, float* __restrict__ a_dst,
    int* __restrict__ gbucket, int* __restrict__ bucket_cur)
{
    __shared__ float xs[64 * 68];   // 17408 B (gemm) / record staging (bin)
    __shared__ float Ws[64 * 64];   // 16384 B (gemm) / counters (bin)
    const int tid = threadIdx.x;

    if (blockIdx.x >= GEMM_BLOCKS) {
        // ---------------- phase-1 LDS bin sort ----------------
        int* recs  = (int*)xs;        // CHUNK records
        int* bcnt  = (int*)Ws;        // [32] counts
        int* lbase = bcnt + 32;       // [32] local exclusive scan
        int* boff  = bcnt + 64;       // [32] placement cursors
        int* gbase = bcnt + 96;       // [32] reserved global bases
        const int blk = blockIdx.x - GEMM_BLOCKS;
        const int e0 = blk * CHUNK;

        for (int i = tid; i < NBUCK; i += 256) { bcnt[i] = 0; boff[i] = 0; }
        __syncthreads();
#pragma unroll
        for (int k = 0; k < CHUNK / 256; ++k) {
            const int e = e0 + k * 256 + tid;
            if (e < NE) atomicAdd(&bcnt[dst[e] >> BSHIFT], 1);
        }
        __syncthreads();
        if (tid == 0) {
            int run = 0;
            for (int b = 0; b < NBUCK; ++b) { lbase[b] = run; run += bcnt[b]; }
        }
        __syncthreads();
        if (tid < NBUCK && bcnt[tid])
            gbase[tid] = atomicAdd(&bucket_cur[tid], bcnt[tid]);
        __syncthreads();
#pragma unroll
        for (int k = 0; k < CHUNK / 256; ++k) {
            const int e = e0 + k * 256 + tid;
            if (e < NE) {
                const int d = dst[e];
                const int b = d >> BSHIFT;
                const int pos = lbase[b] + atomicAdd(&boff[b], 1);
                recs[pos] = (src[e] << BSHIFT) | (d & (BNODES - 1));
            }
        }
        __syncthreads();
        for (int b = 0; b < NBUCK; ++b) {
            const int c = bcnt[b], lb = lbase[b], gb = gbase[b];
            for (int i = tid; i < c; i += 256)
                gbucket[(size_t)b * BUCKCAP + gb + i] = recs[lb + i];
        }
        return;
    }

    // ---------------- GEMM path (64x64 tile, k-chunked) ----------------
    const int block_row = blockIdx.x * 64;
    const int tx = tid & 15, ty = tid >> 4;
    const int r0 = ty * 4, c0 = tx * 4;
    float acc[4][4] = {};

    for (int kc = 0; kc < 128; kc += 64) {
        if (kc) __syncthreads();
        for (int t = tid; t < 64 * 16; t += 256) {
            int r = t >> 4, kv = (t & 15) << 2;
            int row = block_row + r;
            float4 v = make_float4(0.f, 0.f, 0.f, 0.f);
            if (row < NN) v = *(const float4*)(x + (size_t)row * IN_DIM + kc + kv);
            *(float4*)(&xs[r * 68 + kv]) = v;
        }
        for (int t = tid; t < 64 * 16; t += 256) {
            int k = t >> 4, cv = (t & 15) << 2;
            *(float4*)(&Ws[k * 64 + cv]) = *(const float4*)(W + (size_t)(kc + k) * 64 + cv);
        }
        __syncthreads();

        for (int kk = 0; kk < 64; kk += 4) {
            float4 xv[4], wv[4];
#pragma unroll
            for (int i = 0; i < 4; ++i) xv[i] = *(float4*)(&xs[(r0 + i) * 68 + kk]);
#pragma unroll
            for (int t = 0; t < 4; ++t) wv[t] = *(float4*)(&Ws[(kk + t) * 64 + c0]);
#pragma unroll
            for (int i = 0; i < 4; ++i) {
                float xa0 = xv[i].x, xa1 = xv[i].y, xa2 = xv[i].z, xa3 = xv[i].w;
                acc[i][0] += xa0 * wv[0].x + xa1 * wv[1].x + xa2 * wv[2].x + xa3 * wv[3].x;
                acc[i][1] += xa0 * wv[0].y + xa1 * wv[1].y + xa2 * wv[2].y + xa3 * wv[3].y;
                acc[i][2] += xa0 * wv[0].z + xa1 * wv[1].z + xa2 * wv[2].z + xa3 * wv[3].z;
                acc[i][3] += xa0 * wv[0].w + xa1 * wv[1].w + xa2 * wv[2].w + xa3 * wv[3].w;
            }
        }
    }

    float as0 = att_src[c0], as1 = att_src[c0 + 1], as2 = att_src[c0 + 2], as3 = att_src[c0 + 3];
    float ad0 = att_dst[c0], ad1 = att_dst[c0 + 1], ad2 = att_dst[c0 + 2], ad3 = att_dst[c0 + 3];
#pragma unroll
    for (int i = 0; i < 4; ++i) {
        int row = block_row + r0 + i;
        float ps = acc[i][0] * as0 + acc[i][1] * as1 + acc[i][2] * as2 + acc[i][3] * as3;
        float pd = acc[i][0] * ad0 + acc[i][1] * ad1 + acc[i][2] * ad2 + acc[i][3] * ad3;
#pragma unroll
        for (int off = 1; off < 16; off <<= 1) {
            ps += __shfl_xor(ps, off, 64);
            pd += __shfl_xor(pd, off, 64);
        }
        if (row < NN) {
            __half2 p0 = __floats2half2_rn(acc[i][0], acc[i][1]);
            __half2 p1 = __floats2half2_rn(acc[i][2], acc[i][3]);
            uint2 pk;
            pk.x = *(unsigned*)&p0;
            pk.y = *(unsigned*)&p1;
            *(uint2*)(h2 + (size_t)row * OUT_DIM + c0) = pk;
            if (tx == 0) { a_src[row] = ps; a_dst[row] = pd; }
        }
    }
}

// ---- Kernel B: phase-2 scatter, L2-resident per-bucket window --------------
__global__ __launch_bounds__(256) void gat_scat2(
    const int* __restrict__ gbucket, const int* __restrict__ bucket_cur,
    int* __restrict__ cnt, unsigned* __restrict__ entries)
{
    const int b = blockIdx.x / P2_SPLIT;
    const int j = blockIdx.x % P2_SPLIT;
    const int total = bucket_cur[b];
    const int step = (total + P2_SPLIT - 1) / P2_SPLIT;
    const int lo = j * step;
    const int hi = (lo + step < total) ? lo + step : total;
    const int d0 = b << BSHIFT;
    for (int i = lo + threadIdx.x; i < hi; i += 256) {
        const int r = gbucket[(size_t)b * BUCKCAP + i];
        const int s = r >> BSHIFT;
        const int d = d0 + (r & (BNODES - 1));
        const int pos = atomicAdd(&cnt[d], 1);
        if (pos < CAP) entries[((size_t)d << 6) + pos] = (unsigned)s;
    }
}

// ---- Kernel C: per-node wave gather aggregation (prefetched) ---------------
// Lane layout: 8 edge-slots (grp) x 8 column-octs (cq, 8 fp16 = 16B each).
__global__ __launch_bounds__(256) void gat_agg(
    const unsigned* __restrict__ entries, const int* __restrict__ cnt,
    const __half* __restrict__ h2, const float* __restrict__ a_src,
    const float* __restrict__ a_dst, const float* __restrict__ bias,
    float* __restrict__ out)
{
    const int node = blockIdx.x * 4 + (threadIdx.x >> 6);
    if (node >= NN) return;
    const int lane = threadIdx.x & 63;
    const int grp = lane >> 3;
    const int cq = lane & 7;

    int deg = cnt[node];
    if (deg > CAP) deg = CAP;
    const float ad = a_dst[node];
    const unsigned* row = entries + ((size_t)node << 6);

    float v = a_src[node] + ad;
    v = v > 0.f ? v : NEG * v;
    const float exs = __expf(v);
    const float w0 = (grp == 0) ? exs : 0.f;

    float acc[8];
    {
        uint4 hp = *(const uint4*)(h2 + ((size_t)node << 6) + (cq << 3));
        const __half2* hh = (const __half2*)&hp;
#pragma unroll
        for (int j = 0; j < 4; ++j) {
            float2 f = __half22float2(hh[j]);
            acc[2 * j] = w0 * f.x;
            acc[2 * j + 1] = w0 * f.y;
        }
    }
    float den = w0;

    // prefetch iteration 0's entry + a_src
    int sN = (grp < deg) ? (int)row[grp] : -1;
    float aN = (sN >= 0) ? a_src[sN] : 0.f;

    for (int base = 0; base < deg; base += 8) {
        const int s = sN;
        const float av = aN;
        const int e2 = base + 8 + grp;
        sN = (e2 < deg) ? (int)row[e2] : -1;
        aN = (sN >= 0) ? a_src[sN] : 0.f;
        if (s >= 0) {
            float ev = av + ad;
            ev = ev > 0.f ? ev : NEG * ev;
            const float ex = __expf(ev);
            uint4 g = *(const uint4*)(h2 + ((size_t)s << 6) + (cq << 3));
            const __half2* gh = (const __half2*)&g;
#pragma unroll
            for (int j = 0; j < 4; ++j) {
                float2 f = __half22float2(gh[j]);
                acc[2 * j] += ex * f.x;
                acc[2 * j + 1] += ex * f.y;
            }
            den += ex;
        }
    }

#pragma unroll
    for (int off = 8; off < 64; off <<= 1) {
#pragma unroll
        for (int j = 0; j < 8; ++j) acc[j] += __shfl_xor(acc[j], off, 64);
        den += __shfl_xor(den, off, 64);
    }

    if (grp == 0) {
        const float inv = 1.f / den;
        const float4 b0 = *(const float4*)(bias + (cq << 3));
        const float4 b1 = *(const float4*)(bias + (cq << 3) + 4);
        float4 o0, o1;
        o0.x = acc[0] * inv + b0.x; o0.y = acc[1] * inv + b0.y;
        o0.z = acc[2] * inv + b0.z; o0.w = acc[3] * inv + b0.w;
        o1.x = acc[4] * inv + b1.x; o1.y = acc[5] * inv + b1.y;
        o1.z = acc[6] * inv + b1.z; o1.w = acc[7] * inv + b1.w;
        float* op = out + ((size_t)node << 6) + (cq << 3);
        *(float4*)op = o0;
        *(float4*)(op + 4) = o1;
    }
}

extern "C" void kernel_launch(void* const* d_in, const int* in_sizes, int n_in,
                              void* d_out, int out_size, void* d_ws, size_t ws_size,
                              hipStream_t stream) {
    const float* x       = (const float*)d_in[0];
    const int*   eidx    = (const int*)d_in[1];   // [2, NE] row-major
    const float* W       = (const float*)d_in[2];
    const float* att_src = (const float*)d_in[3];
    const float* att_dst = (const float*)d_in[4];
    const float* bias    = (const float*)d_in[5];
    float* out = (float*)d_out;

    // ws: h2 [NN*64 fp16 = 6.4MB] | entries [NN*64 u32 = 12.8MB]
    //   | gbucket [25*36864 int = 3.7MB] | a_src [NN] | a_dst [NN]
    //   | cnt [NN] + bucket_cur [25]  (contiguous -> one memset)
    __half*   h2      = (__half*)d_ws;
    unsigned* entries = (unsigned*)((char*)d_ws + (size_t)NN * OUT_DIM * 2);
    int*      gbucket = (int*)(entries + (size_t)NN * CAP);
    float*    a_src   = (float*)(gbucket + (size_t)NBUCK * BUCKCAP);
    float*    a_dst   = a_src + NN;
    int*      cnt     = (int*)(a_dst + NN);
    int*      bucket_cur = cnt + NN;

    const int* src = eidx;
    const int* dst = eidx + NE;

    hipMemsetAsync(cnt, 0, (NN + NBUCK) * sizeof(int), stream);

    gat_gemm_bin<<<GEMM_BLOCKS + BIN_BLOCKS, 256, 0, stream>>>(
        x, W, att_src, att_dst, src, dst, h2, a_src, a_dst, gbucket, bucket_cur);
    gat_scat2<<<NBUCK * P2_SPLIT, 256, 0, stream>>>(gbucket, bucket_cur, cnt, entries);
    gat_agg<<<(NN + 3) / 4, 256, 0, stream>>>(entries, cnt, h2, a_src, a_dst, bias, out);
}

// Round 7
// 155.032 us; speedup vs baseline: 1.2073x; 1.2073x over previous
//
#include <hip/hip_runtime.h>
#include <hip/hip_fp16.h>

#define NN 50000
#define NE 800000
#define IN_DIM 128
#define OUT_DIM 64
#define NEG 0.2f

#define BSHIFT 8
#define BNODES 256              // nodes per bucket
#define NBUCK 196               // ceil(50000 / 256)
#define BUCKCAP 4736            // mean 4096, +10 sigma
#define CHUNK 4096              // edges per phase-1 bin block
#define BIN_BLOCKS 196          // ceil(NE / CHUNK)
#define GEMM_BLOCKS 782         // ceil(NN / 64)

// ---- Kernel A: fused [h2 = fp16(x@W) + a_src/a_dst] and [edge bin-sort] ----
__global__ __launch_bounds__(256) void gat_gemm_bin(
    const float* __restrict__ x, const float* __restrict__ W,
    const float* __restrict__ att_src, const float* __restrict__ att_dst,
    const int* __restrict__ src, const int* __restrict__ dst,
    __half* __restrict__ h2, float* __restrict__ a_src, float* __restrict__ a_dst,
    int* __restrict__ gbucket, int* __restrict__ bucket_cur)
{
    __shared__ float xs[64 * 68];   // 17408 B  (gemm) / record staging (bin)
    __shared__ float Ws[64 * 64];   // 16384 B  (gemm) / counters+scan (bin)
    const int tid = threadIdx.x;

    if (blockIdx.x >= GEMM_BLOCKS) {
        // ---------------- phase-1 LDS bin sort ----------------
        int* recs  = (int*)xs;        // [CHUNK]
        int* bcnt  = (int*)Ws;        // [256]
        int* scanb = bcnt + 256;      // [256]
        int* boff  = bcnt + 512;      // [256]
        int* gbase = bcnt + 768;      // [256]
        int* lbase = bcnt + 1024;     // [256]
        const int blk = blockIdx.x - GEMM_BLOCKS;
        const int e0 = blk * CHUNK;
        const int total = (e0 + CHUNK < NE ? CHUNK : NE - e0);

        bcnt[tid] = 0; boff[tid] = 0;
        __syncthreads();
#pragma unroll
        for (int k = 0; k < CHUNK / 256; ++k) {
            const int e = e0 + k * 256 + tid;
            if (e < NE) atomicAdd(&bcnt[dst[e] >> BSHIFT], 1);
        }
        __syncthreads();
        // Hillis-Steele inclusive scan of bcnt -> scanb
        scanb[tid] = bcnt[tid];
        __syncthreads();
#pragma unroll
        for (int off = 1; off < 256; off <<= 1) {
            int t = (tid >= off) ? scanb[tid - off] : 0;
            __syncthreads();
            scanb[tid] += t;
            __syncthreads();
        }
        lbase[tid] = scanb[tid] - bcnt[tid];            // exclusive
        if (tid < NBUCK && bcnt[tid])
            gbase[tid] = atomicAdd(&bucket_cur[tid], bcnt[tid]);
        __syncthreads();
        // stage records grouped by bucket
#pragma unroll
        for (int k = 0; k < CHUNK / 256; ++k) {
            const int e = e0 + k * 256 + tid;
            if (e < NE) {
                const int d = dst[e];
                const int b = d >> BSHIFT;
                const int pos = lbase[b] + atomicAdd(&boff[b], 1);
                recs[pos] = (src[e] << BSHIFT) | (d & (BNODES - 1));
            }
        }
        __syncthreads();
        // coalesced flush: binary-search owning bucket per staged index
        for (int j = tid; j < total; j += 256) {
            int lo = 0, hi = NBUCK - 1;
            while (lo < hi) {
                int mid = (lo + hi + 1) >> 1;
                if (lbase[mid] <= j) lo = mid; else hi = mid - 1;
            }
            gbucket[lo * BUCKCAP + gbase[lo] + (j - lbase[lo])] = recs[j];
        }
        return;
    }

    // ---------------- GEMM path (64x64 tile, k-chunked) ----------------
    const int block_row = blockIdx.x * 64;
    const int tx = tid & 15, ty = tid >> 4;
    const int r0 = ty * 4, c0 = tx * 4;
    float acc[4][4] = {};

    for (int kc = 0; kc < 128; kc += 64) {
        if (kc) __syncthreads();
        for (int t = tid; t < 64 * 16; t += 256) {
            int r = t >> 4, kv = (t & 15) << 2;
            int row = block_row + r;
            float4 v = make_float4(0.f, 0.f, 0.f, 0.f);
            if (row < NN) v = *(const float4*)(x + (size_t)row * IN_DIM + kc + kv);
            *(float4*)(&xs[r * 68 + kv]) = v;
        }
        for (int t = tid; t < 64 * 16; t += 256) {
            int k = t >> 4, cv = (t & 15) << 2;
            *(float4*)(&Ws[k * 64 + cv]) = *(const float4*)(W + (size_t)(kc + k) * 64 + cv);
        }
        __syncthreads();

        for (int kk = 0; kk < 64; kk += 4) {
            float4 xv[4], wv[4];
#pragma unroll
            for (int i = 0; i < 4; ++i) xv[i] = *(float4*)(&xs[(r0 + i) * 68 + kk]);
#pragma unroll
            for (int t = 0; t < 4; ++t) wv[t] = *(float4*)(&Ws[(kk + t) * 64 + c0]);
#pragma unroll
            for (int i = 0; i < 4; ++i) {
                float xa0 = xv[i].x, xa1 = xv[i].y, xa2 = xv[i].z, xa3 = xv[i].w;
                acc[i][0] += xa0 * wv[0].x + xa1 * wv[1].x + xa2 * wv[2].x + xa3 * wv[3].x;
                acc[i][1] += xa0 * wv[0].y + xa1 * wv[1].y + xa2 * wv[2].y + xa3 * wv[3].y;
                acc[i][2] += xa0 * wv[0].z + xa1 * wv[1].z + xa2 * wv[2].z + xa3 * wv[3].z;
                acc[i][3] += xa0 * wv[0].w + xa1 * wv[1].w + xa2 * wv[2].w + xa3 * wv[3].w;
            }
        }
    }

    float as0 = att_src[c0], as1 = att_src[c0 + 1], as2 = att_src[c0 + 2], as3 = att_src[c0 + 3];
    float ad0 = att_dst[c0], ad1 = att_dst[c0 + 1], ad2 = att_dst[c0 + 2], ad3 = att_dst[c0 + 3];
#pragma unroll
    for (int i = 0; i < 4; ++i) {
        int row = block_row + r0 + i;
        float ps = acc[i][0] * as0 + acc[i][1] * as1 + acc[i][2] * as2 + acc[i][3] * as3;
        float pd = acc[i][0] * ad0 + acc[i][1] * ad1 + acc[i][2] * ad2 + acc[i][3] * ad3;
#pragma unroll
        for (int off = 1; off < 16; off <<= 1) {
            ps += __shfl_xor(ps, off, 64);
            pd += __shfl_xor(pd, off, 64);
        }
        if (row < NN) {
            __half2 p0 = __floats2half2_rn(acc[i][0], acc[i][1]);
            __half2 p1 = __floats2half2_rn(acc[i][2], acc[i][3]);
            uint2 pk;
            pk.x = *(unsigned*)&p0;
            pk.y = *(unsigned*)&p1;
            *(uint2*)(h2 + (size_t)row * OUT_DIM + c0) = pk;
            if (tx == 0) { a_src[row] = ps; a_dst[row] = pd; }
        }
    }
}

// ---- Kernel B: per-bucket counting sort. ONE block per bucket --------------
// (single writer per output window -> XCD-local L2, no cross-die churn;
//  no global atomics; emits dense CSR: sorted srcs + row_start + cnt)
__global__ __launch_bounds__(256) void gat_sortscat(
    const int* __restrict__ gbucket, const int* __restrict__ bucket_cur,
    unsigned* __restrict__ sorted, int* __restrict__ row_start,
    int* __restrict__ cnt)
{
    __shared__ int recs[BUCKCAP];
    __shared__ int hist[BNODES];
    __shared__ int scanb[BNODES];
    __shared__ int cur[BNODES];
    const int b = blockIdx.x;
    const int tid = threadIdx.x;
    int cnt_b = bucket_cur[b];
    if (cnt_b > BUCKCAP) cnt_b = BUCKCAP;

    hist[tid] = 0;
    __syncthreads();
    for (int i = tid; i < cnt_b; i += 256) {
        const int r = gbucket[(size_t)b * BUCKCAP + i];
        recs[i] = r;
        atomicAdd(&hist[r & (BNODES - 1)], 1);
    }
    __syncthreads();
    scanb[tid] = hist[tid];
    __syncthreads();
#pragma unroll
    for (int off = 1; off < 256; off <<= 1) {
        int t = (tid >= off) ? scanb[tid - off] : 0;
        __syncthreads();
        scanb[tid] += t;
        __syncthreads();
    }
    const int excl = scanb[tid] - hist[tid];
    cur[tid] = excl;
    const int node = (b << BSHIFT) + tid;
    if (node < NN) {
        row_start[node] = b * BUCKCAP + excl;
        cnt[node] = hist[tid];
    }
    __syncthreads();
    for (int i = tid; i < cnt_b; i += 256) {
        const int r = recs[i];
        const int pos = atomicAdd(&cur[r & (BNODES - 1)], 1);
        sorted[(size_t)b * BUCKCAP + pos] = (unsigned)(r >> BSHIFT);
    }
}

// ---- Kernel C: per-node wave gather aggregation, depth-2 pipelined ---------
// Lane layout: 8 edge-slots (grp) x 8 column-octs (cq, 8 fp16 = 16B each).
__global__ __launch_bounds__(256) void gat_agg(
    const unsigned* __restrict__ sorted, const int* __restrict__ row_start,
    const int* __restrict__ cnt, const __half* __restrict__ h2,
    const float* __restrict__ a_src, const float* __restrict__ a_dst,
    const float* __restrict__ bias, float* __restrict__ out)
{
    const int node = blockIdx.x * 4 + (threadIdx.x >> 6);
    if (node >= NN) return;
    const int lane = threadIdx.x & 63;
    const int grp = lane >> 3;
    const int cq = lane & 7;

    const int deg = cnt[node];
    const float ad = a_dst[node];
    const unsigned* row = sorted + row_start[node];

    float v = a_src[node] + ad;
    v = v > 0.f ? v : NEG * v;
    const float exs = __expf(v);
    const float w0 = (grp == 0) ? exs : 0.f;

    float acc[8];
    {
        uint4 hp = *(const uint4*)(h2 + ((size_t)node << 6) + (cq << 3));
        const __half2* hh = (const __half2*)&hp;
#pragma unroll
        for (int j = 0; j < 4; ++j) {
            float2 f = __half22float2(hh[j]);
            acc[2 * j] = w0 * f.x;
            acc[2 * j + 1] = w0 * f.y;
        }
    }
    float den = w0;

    // depth-2 pipeline: prefetch src, a_src AND the h2 row of the next round
    int s = -1; float a = 0.f;
    uint4 g = make_uint4(0, 0, 0, 0);
    if (grp < deg) {
        s = (int)row[grp];
        a = a_src[s];
        g = *(const uint4*)(h2 + ((size_t)s << 6) + (cq << 3));
    }

    for (int base = 0; base < deg; base += 8) {
        int sn = -1; float an = 0.f;
        uint4 gn = make_uint4(0, 0, 0, 0);
        const int en = base + 8 + grp;
        if (en < deg) {
            sn = (int)row[en];
            an = a_src[sn];
            gn = *(const uint4*)(h2 + ((size_t)sn << 6) + (cq << 3));
        }
        if (s >= 0) {
            float ev = a + ad;
            ev = ev > 0.f ? ev : NEG * ev;
            const float ex = __expf(ev);
            const __half2* gh = (const __half2*)&g;
#pragma unroll
            for (int j = 0; j < 4; ++j) {
                float2 f = __half22float2(gh[j]);
                acc[2 * j] += ex * f.x;
                acc[2 * j + 1] += ex * f.y;
            }
            den += ex;
        }
        s = sn; a = an; g = gn;
    }

#pragma unroll
    for (int off = 8; off < 64; off <<= 1) {
#pragma unroll
        for (int j = 0; j < 8; ++j) acc[j] += __shfl_xor(acc[j], off, 64);
        den += __shfl_xor(den, off, 64);
    }

    if (grp == 0) {
        const float inv = 1.f / den;
        const float4 b0 = *(const float4*)(bias + (cq << 3));
        const float4 b1 = *(const float4*)(bias + (cq << 3) + 4);
        float4 o0, o1;
        o0.x = acc[0] * inv + b0.x; o0.y = acc[1] * inv + b0.y;
        o0.z = acc[2] * inv + b0.z; o0.w = acc[3] * inv + b0.w;
        o1.x = acc[4] * inv + b1.x; o1.y = acc[5] * inv + b1.y;
        o1.z = acc[6] * inv + b1.z; o1.w = acc[7] * inv + b1.w;
        float* op = out + ((size_t)node << 6) + (cq << 3);
        *(float4*)op = o0;
        *(float4*)(op + 4) = o1;
    }
}

extern "C" void kernel_launch(void* const* d_in, const int* in_sizes, int n_in,
                              void* d_out, int out_size, void* d_ws, size_t ws_size,
                              hipStream_t stream) {
    const float* x       = (const float*)d_in[0];
    const int*   eidx    = (const int*)d_in[1];   // [2, NE] row-major
    const float* W       = (const float*)d_in[2];
    const float* att_src = (const float*)d_in[3];
    const float* att_dst = (const float*)d_in[4];
    const float* bias    = (const float*)d_in[5];
    float* out = (float*)d_out;

    // ws: h2 [NN*64 fp16 = 6.4MB] | gbucket [196*4736 = 3.7MB]
    //   | sorted [3.7MB] | a_src | a_dst | cnt | row_start | bucket_cur
    __half*   h2      = (__half*)d_ws;
    int*      gbucket = (int*)((char*)d_ws + (size_t)NN * OUT_DIM * 2);
    unsigned* sorted  = (unsigned*)(gbucket + (size_t)NBUCK * BUCKCAP);
    float*    a_src   = (float*)(sorted + (size_t)NBUCK * BUCKCAP);
    float*    a_dst   = a_src + NN;
    int*      cnt     = (int*)(a_dst + NN);
    int*      row_start = cnt + NN;
    int*      bucket_cur = row_start + NN;

    const int* src = eidx;
    const int* dst = eidx + NE;

    hipMemsetAsync(bucket_cur, 0, NBUCK * sizeof(int), stream);

    gat_gemm_bin<<<GEMM_BLOCKS + BIN_BLOCKS, 256, 0, stream>>>(
        x, W, att_src, att_dst, src, dst, h2, a_src, a_dst, gbucket, bucket_cur);
    gat_sortscat<<<NBUCK, 256, 0, stream>>>(gbucket, bucket_cur, sorted, row_start, cnt);
    gat_agg<<<(NN + 3) / 4, 256, 0, stream>>>(sorted, row_start, cnt, h2, a_src, a_dst, bias, out);
}

// Round 8
// 144.553 us; speedup vs baseline: 1.2949x; 1.0725x over previous
//
#include <hip/hip_runtime.h>
#include <hip/hip_fp16.h>

#define NN 50000
#define NE 800000
#define IN_DIM 128
#define OUT_DIM 64
#define NEG 0.2f

#define BSHIFT 8
#define BNODES 256              // nodes per bucket
#define NBUCK 196               // ceil(50000 / 256)
#define BUCKCAP 4736            // mean 4096, +10 sigma
#define CHUNK 4096              // edges per phase-1 bin block
#define BIN_BLOCKS 196          // ceil(NE / CHUNK)
#define GEMM_BLOCKS 782         // ceil(NN / 64)

#define XS_STRIDE 136           // bf16 elems/row: 272 B, 16B-aligned

typedef short short8 __attribute__((ext_vector_type(8)));
typedef float f32x4 __attribute__((ext_vector_type(4)));

__device__ __forceinline__ unsigned short f2bf(float f) {
    unsigned u = __float_as_uint(f);
    u += 0x7FFFu + ((u >> 16) & 1u);
    return (unsigned short)(u >> 16);
}

// ---- Kernel A: fused [h2 = fp16(x@W) via bf16 MFMA + a_src/a_dst] and
//                [edge bin-sort] --------------------------------------------
__global__ __launch_bounds__(256) void gat_gemm_bin(
    const float* __restrict__ x, const float* __restrict__ W,
    const float* __restrict__ att_src, const float* __restrict__ att_dst,
    const int* __restrict__ src, const int* __restrict__ dst,
    unsigned short* __restrict__ h2, float* __restrict__ a_src,
    float* __restrict__ a_dst,
    int* __restrict__ gbucket, int* __restrict__ bucket_cur)
{
    __shared__ __align__(16) unsigned short xs[64 * XS_STRIDE];  // 17408 B
    __shared__ __align__(16) unsigned short wt[64 * XS_STRIDE];  // 17408 B
    const int tid = threadIdx.x;

    if (blockIdx.x >= GEMM_BLOCKS) {
        // ---------------- phase-1 LDS bin sort (unchanged from R7) ---------
        int* recs  = (int*)xs;        // [CHUNK] = 16 KB
        int* bcnt  = (int*)wt;        // [256]
        int* scanb = bcnt + 256;
        int* boff  = bcnt + 512;
        int* gbase = bcnt + 768;
        int* lbase = bcnt + 1024;
        const int blk = blockIdx.x - GEMM_BLOCKS;
        const int e0 = blk * CHUNK;
        const int total = (e0 + CHUNK < NE ? CHUNK : NE - e0);

        bcnt[tid] = 0; boff[tid] = 0;
        __syncthreads();
#pragma unroll
        for (int k = 0; k < CHUNK / 256; ++k) {
            const int e = e0 + k * 256 + tid;
            if (e < NE) atomicAdd(&bcnt[dst[e] >> BSHIFT], 1);
        }
        __syncthreads();
        scanb[tid] = bcnt[tid];
        __syncthreads();
#pragma unroll
        for (int off = 1; off < 256; off <<= 1) {
            int t = (tid >= off) ? scanb[tid - off] : 0;
            __syncthreads();
            scanb[tid] += t;
            __syncthreads();
        }
        lbase[tid] = scanb[tid] - bcnt[tid];
        if (tid < NBUCK && bcnt[tid])
            gbase[tid] = atomicAdd(&bucket_cur[tid], bcnt[tid]);
        __syncthreads();
#pragma unroll
        for (int k = 0; k < CHUNK / 256; ++k) {
            const int e = e0 + k * 256 + tid;
            if (e < NE) {
                const int d = dst[e];
                const int b = d >> BSHIFT;
                const int pos = lbase[b] + atomicAdd(&boff[b], 1);
                recs[pos] = (src[e] << BSHIFT) | (d & (BNODES - 1));
            }
        }
        __syncthreads();
        for (int j = tid; j < total; j += 256) {
            int lo = 0, hi = NBUCK - 1;
            while (lo < hi) {
                int mid = (lo + hi + 1) >> 1;
                if (lbase[mid] <= j) lo = mid; else hi = mid - 1;
            }
            gbucket[lo * BUCKCAP + gbase[lo] + (j - lbase[lo])] = recs[j];
        }
        return;
    }

    // ---------------- GEMM path: bf16 MFMA, 64x64 tile ----------------
    const int block_row = blockIdx.x * 64;

    // stage x tile (64 x 128 f32) -> bf16 LDS
    for (int t = tid; t < 64 * 32; t += 256) {
        const int r = t >> 5, k = (t & 31) << 2;
        const int row = block_row + r;
        float4 v = make_float4(0.f, 0.f, 0.f, 0.f);
        if (row < NN) v = *(const float4*)(x + (size_t)row * IN_DIM + k);
        ushort4 p;
        p.x = f2bf(v.x); p.y = f2bf(v.y); p.z = f2bf(v.z); p.w = f2bf(v.w);
        *(ushort4*)&xs[r * XS_STRIDE + k] = p;
    }
    // stage W^T (wt[n][k]) -> bf16 LDS
    {
        const int n = tid & 63, kq = tid >> 6;
#pragma unroll
        for (int i = 0; i < 32; ++i) {
            const int k = kq * 32 + i;
            wt[n * XS_STRIDE + k] = f2bf(W[k * 64 + n]);
        }
    }
    __syncthreads();

    const int wv = tid >> 6, lane = tid & 63;
    const int m = lane & 15, quad = lane >> 4;

    f32x4 acc[4];
#pragma unroll
    for (int ct = 0; ct < 4; ++ct) acc[ct] = (f32x4){0.f, 0.f, 0.f, 0.f};

    const unsigned short* xrow = &xs[(wv * 16 + m) * XS_STRIDE + quad * 8];
#pragma unroll
    for (int kt = 0; kt < 4; ++kt) {
        short8 af = *(const short8*)(xrow + kt * 32);
#pragma unroll
        for (int ct = 0; ct < 4; ++ct) {
            short8 bf = *(const short8*)(&wt[(ct * 16 + m) * XS_STRIDE + kt * 32 + quad * 8]);
            acc[ct] = __builtin_amdgcn_mfma_f32_16x16x32_bf16(af, bf, acc[ct], 0, 0, 0);
        }
    }

    // epilogue: a_src/a_dst partial dots + 16-lane reduce
    float as_c[4], ad_c[4];
#pragma unroll
    for (int ct = 0; ct < 4; ++ct) {
        as_c[ct] = att_src[ct * 16 + m];
        ad_c[ct] = att_dst[ct * 16 + m];
    }
    float ps[4], pd[4];
#pragma unroll
    for (int reg = 0; reg < 4; ++reg) {
        float s = 0.f, d = 0.f;
#pragma unroll
        for (int ct = 0; ct < 4; ++ct) {
            s += acc[ct][reg] * as_c[ct];
            d += acc[ct][reg] * ad_c[ct];
        }
        ps[reg] = s; pd[reg] = d;
    }
#pragma unroll
    for (int off = 1; off < 16; off <<= 1) {
#pragma unroll
        for (int reg = 0; reg < 4; ++reg) {
            ps[reg] += __shfl_xor(ps[reg], off, 64);
            pd[reg] += __shfl_xor(pd[reg], off, 64);
        }
    }
    if (m == 0) {
#pragma unroll
        for (int reg = 0; reg < 4; ++reg) {
            const int row = block_row + wv * 16 + quad * 4 + reg;
            if (row < NN) { a_src[row] = ps[reg]; a_dst[row] = pd[reg]; }
        }
    }

    // repack C through LDS (fp16) for coalesced h2 stores
    __syncthreads();                       // xs reads done; reuse as hs
    unsigned short* hs = xs;               // 64 rows x stride 72 (144 B)
#pragma unroll
    for (int ct = 0; ct < 4; ++ct)
#pragma unroll
        for (int reg = 0; reg < 4; ++reg)
            hs[(wv * 16 + quad * 4 + reg) * 72 + ct * 16 + m] =
                __half_as_ushort(__float2half(acc[ct][reg]));
    __syncthreads();
    {
        const int r = tid >> 2, c = (tid & 3) * 16;
        const int row = block_row + r;
        if (row < NN) {
            uint4 v0 = *(const uint4*)&hs[r * 72 + c];
            uint4 v1 = *(const uint4*)&hs[r * 72 + c + 8];
            *(uint4*)(h2 + (size_t)row * 64 + c) = v0;
            *(uint4*)(h2 + (size_t)row * 64 + c + 8) = v1;
        }
    }
}

// ---- Kernel B: per-bucket counting sort. ONE block per bucket --------------
__global__ __launch_bounds__(256) void gat_sortscat(
    const int* __restrict__ gbucket, const int* __restrict__ bucket_cur,
    unsigned* __restrict__ sorted, int* __restrict__ row_start,
    int* __restrict__ cnt)
{
    __shared__ int recs[BUCKCAP];
    __shared__ int hist[BNODES];
    __shared__ int scanb[BNODES];
    __shared__ int cur[BNODES];
    const int b = blockIdx.x;
    const int tid = threadIdx.x;
    int cnt_b = bucket_cur[b];
    if (cnt_b > BUCKCAP) cnt_b = BUCKCAP;

    hist[tid] = 0;
    __syncthreads();
    for (int i = tid; i < cnt_b; i += 256) {
        const int r = gbucket[(size_t)b * BUCKCAP + i];
        recs[i] = r;
        atomicAdd(&hist[r & (BNODES - 1)], 1);
    }
    __syncthreads();
    scanb[tid] = hist[tid];
    __syncthreads();
#pragma unroll
    for (int off = 1; off < 256; off <<= 1) {
        int t = (tid >= off) ? scanb[tid - off] : 0;
        __syncthreads();
        scanb[tid] += t;
        __syncthreads();
    }
    const int excl = scanb[tid] - hist[tid];
    cur[tid] = excl;
    const int node = (b << BSHIFT) + tid;
    if (node < NN) {
        row_start[node] = b * BUCKCAP + excl;
        cnt[node] = hist[tid];
    }
    __syncthreads();
    for (int i = tid; i < cnt_b; i += 256) {
        const int r = recs[i];
        const int pos = atomicAdd(&cur[r & (BNODES - 1)], 1);
        sorted[(size_t)b * BUCKCAP + pos] = (unsigned)(r >> BSHIFT);
    }
}

// ---- Kernel C: per-node wave gather aggregation, depth-2 pipelined ---------
__global__ __launch_bounds__(256) void gat_agg(
    const unsigned* __restrict__ sorted, const int* __restrict__ row_start,
    const int* __restrict__ cnt, const __half* __restrict__ h2,
    const float* __restrict__ a_src, const float* __restrict__ a_dst,
    const float* __restrict__ bias, float* __restrict__ out)
{
    const int node = blockIdx.x * 4 + (threadIdx.x >> 6);
    if (node >= NN) return;
    const int lane = threadIdx.x & 63;
    const int grp = lane >> 3;
    const int cq = lane & 7;

    const int deg = cnt[node];
    const float ad = a_dst[node];
    const unsigned* row = sorted + row_start[node];

    float v = a_src[node] + ad;
    v = v > 0.f ? v : NEG * v;
    const float exs = __expf(v);
    const float w0 = (grp == 0) ? exs : 0.f;

    float acc[8];
    {
        uint4 hp = *(const uint4*)(h2 + ((size_t)node << 6) + (cq << 3));
        const __half2* hh = (const __half2*)&hp;
#pragma unroll
        for (int j = 0; j < 4; ++j) {
            float2 f = __half22float2(hh[j]);
            acc[2 * j] = w0 * f.x;
            acc[2 * j + 1] = w0 * f.y;
        }
    }
    float den = w0;

    int s = -1; float a = 0.f;
    uint4 g = make_uint4(0, 0, 0, 0);
    if (grp < deg) {
        s = (int)row[grp];
        a = a_src[s];
        g = *(const uint4*)(h2 + ((size_t)s << 6) + (cq << 3));
    }

    for (int base = 0; base < deg; base += 8) {
        int sn = -1; float an = 0.f;
        uint4 gn = make_uint4(0, 0, 0, 0);
        const int en = base + 8 + grp;
        if (en < deg) {
            sn = (int)row[en];
            an = a_src[sn];
            gn = *(const uint4*)(h2 + ((size_t)sn << 6) + (cq << 3));
        }
        if (s >= 0) {
            float ev = a + ad;
            ev = ev > 0.f ? ev : NEG * ev;
            const float ex = __expf(ev);
            const __half2* gh = (const __half2*)&g;
#pragma unroll
            for (int j = 0; j < 4; ++j) {
                float2 f = __half22float2(gh[j]);
                acc[2 * j] += ex * f.x;
                acc[2 * j + 1] += ex * f.y;
            }
            den += ex;
        }
        s = sn; a = an; g = gn;
    }

#pragma unroll
    for (int off = 8; off < 64; off <<= 1) {
#pragma unroll
        for (int j = 0; j < 8; ++j) acc[j] += __shfl_xor(acc[j], off, 64);
        den += __shfl_xor(den, off, 64);
    }

    if (grp == 0) {
        const float inv = 1.f / den;
        const float4 b0 = *(const float4*)(bias + (cq << 3));
        const float4 b1 = *(const float4*)(bias + (cq << 3) + 4);
        float4 o0, o1;
        o0.x = acc[0] * inv + b0.x; o0.y = acc[1] * inv + b0.y;
        o0.z = acc[2] * inv + b0.z; o0.w = acc[3] * inv + b0.w;
        o1.x = acc[4] * inv + b1.x; o1.y = acc[5] * inv + b1.y;
        o1.z = acc[6] * inv + b1.z; o1.w = acc[7] * inv + b1.w;
        float* op = out + ((size_t)node << 6) + (cq << 3);
        *(float4*)op = o0;
        *(float4*)(op + 4) = o1;
    }
}

extern "C" void kernel_launch(void* const* d_in, const int* in_sizes, int n_in,
                              void* d_out, int out_size, void* d_ws, size_t ws_size,
                              hipStream_t stream) {
    const float* x       = (const float*)d_in[0];
    const int*   eidx    = (const int*)d_in[1];   // [2, NE] row-major
    const float* W       = (const float*)d_in[2];
    const float* att_src = (const float*)d_in[3];
    const float* att_dst = (const float*)d_in[4];
    const float* bias    = (const float*)d_in[5];
    float* out = (float*)d_out;

    // ws: h2 [NN*64 fp16 = 6.4MB] | gbucket [196*4736 = 3.7MB]
    //   | sorted [3.7MB] | a_src | a_dst | cnt | row_start | bucket_cur
    unsigned short* h2 = (unsigned short*)d_ws;
    int*      gbucket = (int*)((char*)d_ws + (size_t)NN * OUT_DIM * 2);
    unsigned* sorted  = (unsigned*)(gbucket + (size_t)NBUCK * BUCKCAP);
    float*    a_src   = (float*)(sorted + (size_t)NBUCK * BUCKCAP);
    float*    a_dst   = a_src + NN;
    int*      cnt     = (int*)(a_dst + NN);
    int*      row_start = cnt + NN;
    int*      bucket_cur = row_start + NN;

    const int* src = eidx;
    const int* dst = eidx + NE;

    hipMemsetAsync(bucket_cur, 0, NBUCK * sizeof(int), stream);

    gat_gemm_bin<<<GEMM_BLOCKS + BIN_BLOCKS, 256, 0, stream>>>(
        x, W, att_src, att_dst, src, dst, h2, a_src, a_dst, gbucket, bucket_cur);
    gat_sortscat<<<NBUCK, 256, 0, stream>>>(gbucket, bucket_cur, sorted, row_start, cnt);
    gat_agg<<<(NN + 3) / 4, 256, 0, stream>>>(sorted, row_start, cnt,
                                              (const __half*)h2, a_src, a_dst, bias, out);
}